// Round 1
// baseline (452.082 us; speedup 1.0000x reference)
//
#include <hip/hip_runtime.h>
#include <hip/hip_bf16.h>
#include <stdint.h>

// Problem constants
#define INPUT_SIZE   736
#define PLANE_ELEMS  (736*736)        // 541696
#define N_RINGS      368
#define PATCH_LEN    768
#define EMBED        768
#define BATCH        32
#define KDIM         768              // 3*16*16
#define M_TOTAL      (BATCH*23*48)    // 35328 = 276*128
#define P_PER_BATCH  1104             // 23*48
#define OUT_BATCH_STRIDE 847872       // 768*1104
#define GATHER_T     (N_RINGS*PATCH_LEN)   // 282624 table entries

typedef __bf16 bf16x8 __attribute__((ext_vector_type(8)));
typedef float  floatx4 __attribute__((ext_vector_type(4)));

static __device__ __forceinline__ unsigned short bf16bits(float f) {
    __hip_bfloat16 h = __float2bfloat16(f);
    return *reinterpret_cast<unsigned short*>(&h);
}

// ---------------------------------------------------------------------------
// Kernel 1: cast conv_w (fp32, [E=768][K=768] flat) -> bf16 Wb
// ---------------------------------------------------------------------------
__global__ void wcast_kernel(const float* __restrict__ wsrc,
                             __hip_bfloat16* __restrict__ Wb) {
    int i = blockIdx.x * 256 + threadIdx.x;   // grid covers 589824 exactly
    Wb[i] = __float2bfloat16(wsrc[i]);
}

// ---------------------------------------------------------------------------
// Kernel 1b: pack (idx0, idx1, w) -> 8B record {i0, (w16<<16)|(i1-i0)}
//   R4: gather was VMEM-instruction-bound (6 lane-ops/output at ~2 addr/cy/CU
//   = 318K cy/CU = the observed 133us). Packing the three bookkeeping streams
//   into one 8B record lets the gather fetch TWO outputs' metadata with a
//   single dwordx4. w as 16-bit fixed point: error <= 2^-16 * |g1-g0|,
//   negligible vs the bf16 rounding of A. Delta i1-i0 is a within-ring
//   neighbor step (|d| < ~2.5K), comfortably inside int16.
// ---------------------------------------------------------------------------
__global__ void pack_kernel(const int*   __restrict__ idx0,
                            const int*   __restrict__ idx1,
                            const float* __restrict__ w,
                            int2* __restrict__ P) {
    int t = blockIdx.x * 256 + threadIdx.x;   // grid 1104*256 = 282624 exact
    int i0 = idx0[t];
    int d  = idx1[t] - i0;
    unsigned w16 = (unsigned)(w[t] * 65536.0f);   // w<1 -> trunc <= 65535
    if (w16 > 65535u) w16 = 65535u;               // guard fp rounding
    P[t] = make_int2(i0, (int)((w16 << 16) | ((unsigned)d & 0xFFFFu)));
}

// ---------------------------------------------------------------------------
// Kernel 2: gather + lerp -> A[m][k] bf16 (GEMM A operand, K-contiguous)
//   R4 restructure: thread owns 2 CONSECUTIVE angles. Per iter:
//     1 x int4  load  (packed records for both outputs)   0.5 lane-op/output
//     4 x scattered plane loads                           2.0 lane-op/output
//     1 x ushort2 store (2 consecutive k)                 0.5 lane-op/output
//   => 3.0 VMEM lane-ops/output vs 6.0 before. Wave arc span per scattered
//   instruction grows 16->32 angles; repeat touches are L1 hits, and FETCH
//   was already ~1.16x the image, so line traffic stays non-binding.
// ---------------------------------------------------------------------------
__global__ void gather_kernel(const float* __restrict__ x,
                              const int2*  __restrict__ P,
                              __hip_bfloat16* __restrict__ A) {
    int b    = blockIdx.x;          // ((n*3+c)*23 + band)*2 + half
    int half = b & 1;
    int bb   = b >> 1;
    int band = bb % 23;
    int nc   = bb / 23;             // n*3+c
    int c    = nc % 3;
    int n    = nc / 3;
    const float* plane = x + (size_t)nc * PLANE_ELEMS;

    int rr = threadIdx.x >> 4;      // ring within band, 0..15
    int jj = threadIdx.x & 15;      // angle-pair slot, 0..15 (angles jj*2, jj*2+1)
    int r  = band * 16 + rr;
    int tbase = r * PATCH_LEN + half * 384 + jj * 2;

    // Output addressing: angle = half*384 + it*32 + jj*2 + e (e=0,1)
    //   patch col = half*24 + it*2 + (jj>>3);  k = c*256 + rr*16 + (jj&7)*2 + e
    int k = c * 256 + rr * 16 + (jj & 7) * 2;
    size_t mbase = (size_t)(n * P_PER_BATCH + band * 48 + half * 24 + (jj >> 3));
    __hip_bfloat16* aptr = A + mbase * KDIM + k;

    #pragma unroll 4
    for (int it = 0; it < 12; it++) {
        int4 q = *reinterpret_cast<const int4*>(&P[tbase + it * 32]); // 16B aligned
        // output a (even angle)
        int   i0a = q.x;
        int   i1a = i0a + (int)(short)((unsigned)q.y & 0xFFFFu);
        float wa  = (float)((unsigned)q.y >> 16) * (1.0f / 65536.0f);
        float va  = plane[i0a] * (1.0f - wa) + plane[i1a] * wa;
        // output b (odd angle)
        int   i0b = q.z;
        int   i1b = i0b + (int)(short)((unsigned)q.w & 0xFFFFu);
        float wb  = (float)((unsigned)q.w >> 16) * (1.0f / 65536.0f);
        float vb  = plane[i0b] * (1.0f - wb) + plane[i1b] * wb;
        // paired store: 2 consecutive k -> one 4B store
        *reinterpret_cast<ushort2*>(aptr + (size_t)(it * 2) * KDIM) =
            make_ushort2(bf16bits(va), bf16bits(vb));
    }
}

// ---------------------------------------------------------------------------
// Kernel 3: GEMM  C[m][e] = sum_k A[m][k] * Wb[e][k]  + bias[e]   (unchanged)
//   M=35328 (276 tiles), E=768 (6 tiles), K=768 (24 x BK=32)
//   128x128 tile, 4 waves, each wave = 64x64 via 4x4 grid of 16x16x32 MFMA.
// ---------------------------------------------------------------------------
__global__ __launch_bounds__(256) void gemm_kernel(
        const __hip_bfloat16* __restrict__ A,   // [35328][768]
        const __hip_bfloat16* __restrict__ Wb,  // [768][768] (E,K) = B^T
        const float* __restrict__ cb,           // [768]
        float* __restrict__ out)                // [32][768][1104]
{
    __shared__ __hip_bfloat16 As[128 * 32];
    __shared__ __hip_bfloat16 Bs[128 * 32];

    const int tid  = threadIdx.x;
    const int lane = tid & 63;
    const int wv   = tid >> 6;
    const int wm   = wv & 1;      // wave row (0..1)
    const int wn   = wv >> 1;     // wave col (0..1)
    const int quad = lane >> 4;
    const int l16  = lane & 15;

    const int bn = blockIdx.x;    // 0..5   (embed tiles)
    const int bm = blockIdx.y;    // 0..275 (m tiles)

    floatx4 acc[4][4];
    #pragma unroll
    for (int i = 0; i < 4; i++)
        #pragma unroll
        for (int j = 0; j < 4; j++)
            acc[i][j] = (floatx4){0.f, 0.f, 0.f, 0.f};

    // staging addresses: thread t loads 16B = 8 bf16; row = t>>2, kseg=(t&3)*8
    const int srow = tid >> 2;          // 0..63
    const int kofs = (tid & 3) * 8;     // 0,8,16,24
    const __hip_bfloat16* aSrc = A  + (size_t)(bm * 128 + srow) * KDIM + kofs;
    const __hip_bfloat16* bSrc = Wb + (size_t)(bn * 128 + srow) * KDIM + kofs;
    __hip_bfloat16* aDst = As + tid * 8;        // lane*16B within wave region
    __hip_bfloat16* bDst = Bs + tid * 8;

    for (int kt = 0; kt < 24; kt++) {
        const __hip_bfloat16* ap = aSrc + kt * 32;
        const __hip_bfloat16* bp = bSrc + kt * 32;
        __builtin_amdgcn_global_load_lds(
            (const __attribute__((address_space(1))) void*)(const void*)ap,
            (__attribute__((address_space(3))) void*)(void*)aDst, 16, 0, 0);
        __builtin_amdgcn_global_load_lds(
            (const __attribute__((address_space(1))) void*)(const void*)(ap + (size_t)64 * KDIM),
            (__attribute__((address_space(3))) void*)(void*)(aDst + 64 * 32), 16, 0, 0);
        __builtin_amdgcn_global_load_lds(
            (const __attribute__((address_space(1))) void*)(const void*)bp,
            (__attribute__((address_space(3))) void*)(void*)bDst, 16, 0, 0);
        __builtin_amdgcn_global_load_lds(
            (const __attribute__((address_space(1))) void*)(const void*)(bp + (size_t)64 * KDIM),
            (__attribute__((address_space(3))) void*)(void*)(bDst + 64 * 32), 16, 0, 0);
        __syncthreads();   // drains vmcnt + barrier

        bf16x8 af[4], bfr[4];
        #pragma unroll
        for (int mi = 0; mi < 4; mi++) {
            int ml = wm * 64 + mi * 16 + l16;
            af[mi] = *(const bf16x8*)(As + ml * 32 + quad * 8);
        }
        #pragma unroll
        for (int ni = 0; ni < 4; ni++) {
            int el = wn * 64 + ni * 16 + l16;
            bfr[ni] = *(const bf16x8*)(Bs + el * 32 + quad * 8);
        }
        #pragma unroll
        for (int mi = 0; mi < 4; mi++)
            #pragma unroll
            for (int ni = 0; ni < 4; ni++)
                acc[mi][ni] = __builtin_amdgcn_mfma_f32_16x16x32_bf16(
                                  af[mi], bfr[ni], acc[mi][ni], 0, 0, 0);
        __syncthreads();   // protect As/Bs before next staging
    }

    // ---------------- epilogue: direct float4 stores ----------------------
    const int m0 = bm * 128 + wm * 64;
    const int e0 = bn * 128 + wn * 64;
    #pragma unroll
    for (int ni = 0; ni < 4; ni++) {
        int eg = e0 + ni * 16 + l16;
        float bias = cb[eg];
        #pragma unroll
        for (int mi = 0; mi < 4; mi++) {
            int mg = m0 + mi * 16 + quad * 4;
            int nb = mg / P_PER_BATCH;          // magic-mul
            int p  = mg - nb * P_PER_BATCH;
            floatx4 v = acc[mi][ni];
            v[0] += bias; v[1] += bias; v[2] += bias; v[3] += bias;
            *(floatx4*)(out + (size_t)nb * OUT_BATCH_STRIDE
                            + (size_t)eg * P_PER_BATCH + p) = v;
        }
    }
}

// ---------------------------------------------------------------------------
extern "C" void kernel_launch(void* const* d_in, const int* in_sizes, int n_in,
                              void* d_out, int out_size, void* d_ws, size_t ws_size,
                              hipStream_t stream) {
    const float* x      = (const float*)d_in[0];   // (32,3,736,736)
    const float* conv_w = (const float*)d_in[1];   // (768,3,16,16) = (768,768)
    const float* conv_b = (const float*)d_in[2];   // (768,)
    const int*   idx0   = (const int*)  d_in[3];   // (368*768,)
    const int*   idx1   = (const int*)  d_in[4];
    const float* w      = (const float*)d_in[5];
    float* out = (float*)d_out;

    __hip_bfloat16* A  = (__hip_bfloat16*)d_ws;                 // 54.3 MB
    __hip_bfloat16* Wb = A + (size_t)M_TOTAL * KDIM;            // +1.2 MB
    int2*           P  = (int2*)(Wb + (size_t)EMBED * KDIM);    // +2.3 MB

    // 1) weight cast: 589824 elements
    wcast_kernel<<<dim3(EMBED * KDIM / 256), dim3(256), 0, stream>>>(conv_w, Wb);

    // 1b) pack gather tables: 282624 entries
    pack_kernel<<<dim3(GATHER_T / 256), dim3(256), 0, stream>>>(idx0, idx1, w, P);

    // 2) gather+lerp -> A : one block per (n, c, band, half)
    gather_kernel<<<dim3(BATCH * 3 * (N_RINGS / 16) * 2), dim3(256), 0, stream>>>(
        x, P, A);

    // 3) GEMM + bias -> out
    gemm_kernel<<<dim3(EMBED / 128, M_TOTAL / 128), dim3(256), 0, stream>>>(
        A, Wb, conv_b, out);
}

// Round 2
// 440.693 us; speedup vs baseline: 1.0258x; 1.0258x over previous
//
#include <hip/hip_runtime.h>
#include <hip/hip_bf16.h>
#include <stdint.h>

// Problem constants
#define INPUT_SIZE   736
#define PLANE_ELEMS  (736*736)        // 541696
#define N_RINGS      368
#define PATCH_LEN    768
#define EMBED        768
#define BATCH        32
#define KDIM         768              // 3*16*16
#define M_TOTAL      (BATCH*23*48)    // 35328 = 276*128
#define P_PER_BATCH  1104             // 23*48
#define OUT_BATCH_STRIDE 847872       // 768*1104
#define GATHER_T     (N_RINGS*PATCH_LEN)   // 282624 table entries

typedef __bf16 bf16x8 __attribute__((ext_vector_type(8)));
typedef float  floatx4 __attribute__((ext_vector_type(4)));

static __device__ __forceinline__ unsigned short bf16bits(float f) {
    __hip_bfloat16 h = __float2bfloat16(f);
    return *reinterpret_cast<unsigned short*>(&h);
}

// ---------------------------------------------------------------------------
// Kernel 1: cast conv_w (fp32, [E=768][K=768] flat) -> bf16 Wb
// ---------------------------------------------------------------------------
__global__ void wcast_kernel(const float* __restrict__ wsrc,
                             __hip_bfloat16* __restrict__ Wb) {
    int i = blockIdx.x * 256 + threadIdx.x;   // grid covers 589824 exactly
    Wb[i] = __float2bfloat16(wsrc[i]);
}

// ---------------------------------------------------------------------------
// Kernel 1b: pack (idx0, idx1, w) -> 8B record {i0, (w16<<16)|(i1-i0)}
//   w as 16-bit fixed point: error <= 2^-16, negligible vs bf16 rounding.
// ---------------------------------------------------------------------------
__global__ void pack_kernel(const int*   __restrict__ idx0,
                            const int*   __restrict__ idx1,
                            const float* __restrict__ w,
                            int2* __restrict__ P) {
    int t = blockIdx.x * 256 + threadIdx.x;   // grid 1104*256 = 282624 exact
    int i0 = idx0[t];
    int d  = idx1[t] - i0;
    unsigned w16 = (unsigned)(w[t] * 65536.0f);   // w<1 -> trunc <= 65535
    if (w16 > 65535u) w16 = 65535u;               // guard fp rounding
    P[t] = make_int2(i0, (int)((w16 << 16) | ((unsigned)d & 0xFFFFu)));
}

// ---------------------------------------------------------------------------
// Kernel 2: gather + lerp -> A[m][k] bf16 (GEMM A operand, K-contiguous)
//   R5: gather is bound by divergent-address LINE REQUESTS (R4 halved VMEM
//   instructions with zero gain -> not instruction-bound; HBM 26%, VALU 6%,
//   occupancy 65% -> the saturated resource is the L1/TA per-line request
//   path, ~1 line/cy/CU). Fix: make each wave's scattered footprint 2-D in
//   polar space. Lane map = 16 rings x 4 angle-pairs (was 4 rings x 16
//   pairs): radially-adjacent samples at equal angle are spatially adjacent
//   pixels, so the wave touches a compact ~16x8..20px rotated patch
//   (~18-23 lines) instead of four 1px-wide arcs (~50-64 lines). Per-thread
//   instruction mix identical to R4 (1 int4 + 4 scattered + 1 ushort2) ->
//   clean A/B on address coherence.
//   Wave w: aw=w>>1 selects angle-block (2 per iteration), hb=w&1 selects
//   which 8 angles of the block. Stores: 16 segments x 16B per wave (L2
//   merges; R4 showed no write amplification with the same granularity).
// ---------------------------------------------------------------------------
__global__ void gather_kernel(const float* __restrict__ x,
                              const int2*  __restrict__ P,
                              __hip_bfloat16* __restrict__ A) {
    int b    = blockIdx.x;          // ((n*3+c)*23 + band)*2 + half
    int half = b & 1;
    int bb   = b >> 1;
    int band = bb % 23;
    int nc   = bb / 23;             // n*3+c
    int c    = nc % 3;
    int n    = nc / 3;
    const float* plane = x + (size_t)nc * PLANE_ELEMS;

    int wv   = threadIdx.x >> 6;    // wave 0..3
    int lane = threadIdx.x & 63;
    int rr   = lane >> 2;           // ring within band, 0..15  (radial-major!)
    int ps   = lane & 3;            // angle-pair slot, 0..3 (angles ps*2, +1)
    int aw   = wv >> 1;             // which of 2 angle-blocks this iteration
    int hb   = wv & 1;              // half-block: angles [hb*8, hb*8+8)
    int r    = band * 16 + rr;

    int tbase = r * PATCH_LEN + half * 384 + aw * 16 + hb * 8 + ps * 2;
    int k     = c * 256 + rr * 16 + hb * 8 + ps * 2;
    size_t mbase = (size_t)(n * P_PER_BATCH + band * 48 + half * 24 + aw);
    __hip_bfloat16* aptr = A + mbase * KDIM + k;

    #pragma unroll 4
    for (int it = 0; it < 12; it++) {
        int4 q = *reinterpret_cast<const int4*>(&P[tbase + it * 32]); // 16B aligned
        // output a (even angle)
        int   i0a = q.x;
        int   i1a = i0a + (int)(short)((unsigned)q.y & 0xFFFFu);
        float wa  = (float)((unsigned)q.y >> 16) * (1.0f / 65536.0f);
        float va  = plane[i0a] * (1.0f - wa) + plane[i1a] * wa;
        // output b (odd angle)
        int   i0b = q.z;
        int   i1b = i0b + (int)(short)((unsigned)q.w & 0xFFFFu);
        float wb  = (float)((unsigned)q.w >> 16) * (1.0f / 65536.0f);
        float vb  = plane[i0b] * (1.0f - wb) + plane[i1b] * wb;
        // paired store: 2 consecutive k -> one 4B store
        *reinterpret_cast<ushort2*>(aptr + (size_t)(it * 2) * KDIM) =
            make_ushort2(bf16bits(va), bf16bits(vb));
    }
}

// ---------------------------------------------------------------------------
// Kernel 3: GEMM  C[m][e] = sum_k A[m][k] * Wb[e][k]  + bias[e]   (unchanged)
//   M=35328 (276 tiles), E=768 (6 tiles), K=768 (24 x BK=32)
//   128x128 tile, 4 waves, each wave = 64x64 via 4x4 grid of 16x16x32 MFMA.
// ---------------------------------------------------------------------------
__global__ __launch_bounds__(256) void gemm_kernel(
        const __hip_bfloat16* __restrict__ A,   // [35328][768]
        const __hip_bfloat16* __restrict__ Wb,  // [768][768] (E,K) = B^T
        const float* __restrict__ cb,           // [768]
        float* __restrict__ out)                // [32][768][1104]
{
    __shared__ __hip_bfloat16 As[128 * 32];
    __shared__ __hip_bfloat16 Bs[128 * 32];

    const int tid  = threadIdx.x;
    const int lane = tid & 63;
    const int wv   = tid >> 6;
    const int wm   = wv & 1;      // wave row (0..1)
    const int wn   = wv >> 1;     // wave col (0..1)
    const int quad = lane >> 4;
    const int l16  = lane & 15;

    const int bn = blockIdx.x;    // 0..5   (embed tiles)
    const int bm = blockIdx.y;    // 0..275 (m tiles)

    floatx4 acc[4][4];
    #pragma unroll
    for (int i = 0; i < 4; i++)
        #pragma unroll
        for (int j = 0; j < 4; j++)
            acc[i][j] = (floatx4){0.f, 0.f, 0.f, 0.f};

    // staging addresses: thread t loads 16B = 8 bf16; row = t>>2, kseg=(t&3)*8
    const int srow = tid >> 2;          // 0..63
    const int kofs = (tid & 3) * 8;     // 0,8,16,24
    const __hip_bfloat16* aSrc = A  + (size_t)(bm * 128 + srow) * KDIM + kofs;
    const __hip_bfloat16* bSrc = Wb + (size_t)(bn * 128 + srow) * KDIM + kofs;
    __hip_bfloat16* aDst = As + tid * 8;        // lane*16B within wave region
    __hip_bfloat16* bDst = Bs + tid * 8;

    for (int kt = 0; kt < 24; kt++) {
        const __hip_bfloat16* ap = aSrc + kt * 32;
        const __hip_bfloat16* bp = bSrc + kt * 32;
        __builtin_amdgcn_global_load_lds(
            (const __attribute__((address_space(1))) void*)(const void*)ap,
            (__attribute__((address_space(3))) void*)(void*)aDst, 16, 0, 0);
        __builtin_amdgcn_global_load_lds(
            (const __attribute__((address_space(1))) void*)(const void*)(ap + (size_t)64 * KDIM),
            (__attribute__((address_space(3))) void*)(void*)(aDst + 64 * 32), 16, 0, 0);
        __builtin_amdgcn_global_load_lds(
            (const __attribute__((address_space(1))) void*)(const void*)bp,
            (__attribute__((address_space(3))) void*)(void*)bDst, 16, 0, 0);
        __builtin_amdgcn_global_load_lds(
            (const __attribute__((address_space(1))) void*)(const void*)(bp + (size_t)64 * KDIM),
            (__attribute__((address_space(3))) void*)(void*)(bDst + 64 * 32), 16, 0, 0);
        __syncthreads();   // drains vmcnt + barrier

        bf16x8 af[4], bfr[4];
        #pragma unroll
        for (int mi = 0; mi < 4; mi++) {
            int ml = wm * 64 + mi * 16 + l16;
            af[mi] = *(const bf16x8*)(As + ml * 32 + quad * 8);
        }
        #pragma unroll
        for (int ni = 0; ni < 4; ni++) {
            int el = wn * 64 + ni * 16 + l16;
            bfr[ni] = *(const bf16x8*)(Bs + el * 32 + quad * 8);
        }
        #pragma unroll
        for (int mi = 0; mi < 4; mi++)
            #pragma unroll
            for (int ni = 0; ni < 4; ni++)
                acc[mi][ni] = __builtin_amdgcn_mfma_f32_16x16x32_bf16(
                                  af[mi], bfr[ni], acc[mi][ni], 0, 0, 0);
        __syncthreads();   // protect As/Bs before next staging
    }

    // ---------------- epilogue: direct float4 stores ----------------------
    const int m0 = bm * 128 + wm * 64;
    const int e0 = bn * 128 + wn * 64;
    #pragma unroll
    for (int ni = 0; ni < 4; ni++) {
        int eg = e0 + ni * 16 + l16;
        float bias = cb[eg];
        #pragma unroll
        for (int mi = 0; mi < 4; mi++) {
            int mg = m0 + mi * 16 + quad * 4;
            int nb = mg / P_PER_BATCH;          // magic-mul
            int p  = mg - nb * P_PER_BATCH;
            floatx4 v = acc[mi][ni];
            v[0] += bias; v[1] += bias; v[2] += bias; v[3] += bias;
            *(floatx4*)(out + (size_t)nb * OUT_BATCH_STRIDE
                            + (size_t)eg * P_PER_BATCH + p) = v;
        }
    }
}

// ---------------------------------------------------------------------------
extern "C" void kernel_launch(void* const* d_in, const int* in_sizes, int n_in,
                              void* d_out, int out_size, void* d_ws, size_t ws_size,
                              hipStream_t stream) {
    const float* x      = (const float*)d_in[0];   // (32,3,736,736)
    const float* conv_w = (const float*)d_in[1];   // (768,3,16,16) = (768,768)
    const float* conv_b = (const float*)d_in[2];   // (768,)
    const int*   idx0   = (const int*)  d_in[3];   // (368*768,)
    const int*   idx1   = (const int*)  d_in[4];
    const float* w      = (const float*)d_in[5];
    float* out = (float*)d_out;

    __hip_bfloat16* A  = (__hip_bfloat16*)d_ws;                 // 54.3 MB
    __hip_bfloat16* Wb = A + (size_t)M_TOTAL * KDIM;            // +1.2 MB
    int2*           P  = (int2*)(Wb + (size_t)EMBED * KDIM);    // +2.3 MB

    // 1) weight cast: 589824 elements
    wcast_kernel<<<dim3(EMBED * KDIM / 256), dim3(256), 0, stream>>>(conv_w, Wb);

    // 1b) pack gather tables: 282624 entries
    pack_kernel<<<dim3(GATHER_T / 256), dim3(256), 0, stream>>>(idx0, idx1, w, P);

    // 2) gather+lerp -> A : one block per (n, c, band, half)
    gather_kernel<<<dim3(BATCH * 3 * (N_RINGS / 16) * 2), dim3(256), 0, stream>>>(
        x, P, A);

    // 3) GEMM + bias -> out
    gemm_kernel<<<dim3(EMBED / 128, M_TOTAL / 128), dim3(256), 0, stream>>>(
        A, Wb, conv_b, out);
}